// Round 3
// baseline (499.883 us; speedup 1.0000x reference)
//
#include <hip/hip_runtime.h>

typedef unsigned short ushort_t;
typedef __attribute__((ext_vector_type(8))) short short8;
typedef __attribute__((ext_vector_type(4))) float f32x4;
typedef __attribute__((ext_vector_type(4))) unsigned short ushort4_t;

// Problem constants
#define BB 2
#define SS 2048
#define EE 1024
#define HH 16
#define DD 64
#define MM (BB*SS)   // 4096

// Workspace layout (ushort element offsets)
#define QB_OFF  0u          // q bf16 [M][E]; reused as ctx bf16 [M][E] after gemm_qkv
#define KB_OFF  4194304u
#define VB_OFF  8388608u
#define WQ_OFF  12582912u   // Wq bf16 [E][E]
#define WK_OFF  13631488u
#define WV_OFF  14680064u
#define WO_OFF  15728640u
#define QH_OFF  16777216u   // Qh bf16 [B][H][S][D] (pre-scaled by 0.125*log2e)
#define KH_OFF  20971520u   // Kh bf16 [B][H][S][D]
#define VT_OFF  25165824u   // VhT bf16 [B][H][D][S'] (S k'-permuted per 128-block)
#define CTX_OFF QB_OFF      // ctx aliases dead q-bf16 region
#define MB_OFF  29360128u   // maskbitsT u32 [B][S(sk)][S/32] (byte off = 2*MB_OFF)

__device__ __forceinline__ ushort_t f2bf(float x) {
    unsigned u = __builtin_bit_cast(unsigned, x);
    u += 0x7FFFu + ((u >> 16) & 1u);
    return (ushort_t)(u >> 16);
}

__device__ __forceinline__ void load_lds16(const void* g, void* l) {
    __builtin_amdgcn_global_load_lds((const __attribute__((address_space(1))) void*)g,
                                     (__attribute__((address_space(3))) void*)l, 16, 0, 0);
}

// ---------------------------------------------------------------------------
// Kernel 1: cast fp32->bf16 (q,k,v,Wq,Wk,Wv,Wo) + transposed mask bit-pack
// ---------------------------------------------------------------------------
__global__ __launch_bounds__(256) void prep_kernel(
    const float* __restrict__ q, const float* __restrict__ k, const float* __restrict__ v,
    const int* __restrict__ mask,
    const float* __restrict__ Wq, const float* __restrict__ Wk,
    const float* __restrict__ Wv, const float* __restrict__ Wo,
    ushort_t* __restrict__ wsb, unsigned* __restrict__ maskbits)
{
    int g = blockIdx.x;
    if (g < 16384) {
        int idx = g * 256 + threadIdx.x;  // float4 index
        const float* src; ushort_t* dst; int rel;
        if      (idx < 1048576) { src = q;  dst = wsb + QB_OFF; rel = idx; }
        else if (idx < 2097152) { src = k;  dst = wsb + KB_OFF; rel = idx - 1048576; }
        else if (idx < 3145728) { src = v;  dst = wsb + VB_OFF; rel = idx - 2097152; }
        else if (idx < 3407872) { src = Wq; dst = wsb + WQ_OFF; rel = idx - 3145728; }
        else if (idx < 3670016) { src = Wk; dst = wsb + WK_OFF; rel = idx - 3407872; }
        else if (idx < 3932160) { src = Wv; dst = wsb + WV_OFF; rel = idx - 3670016; }
        else                    { src = Wo; dst = wsb + WO_OFF; rel = idx - 3932160; }
        f32x4 val = ((const f32x4*)src)[rel];
        ushort4_t o;
        o.x = f2bf(val.x); o.y = f2bf(val.y); o.z = f2bf(val.z); o.w = f2bf(val.w);
        ((ushort4_t*)dst)[rel] = o;
    } else {
        // maskbitsT[b][sk][w] bit j = (mask[b][0][w*32+j][sk] != 0)
        int t = (g - 16384) * 256 + threadIdx.x;   // 0..262143
        int b   = t >> 17;
        int rem = t & 131071;
        int w   = rem >> 11;        // 0..63
        int sk  = rem & 2047;       // consecutive lanes -> consecutive sk (coalesced loads)
        unsigned bits = 0;
        const int* mp = mask + ((size_t)b * SS + (size_t)w * 32) * SS + sk;
        #pragma unroll
        for (int jj = 0; jj < 32; ++jj)
            bits |= (mp[(size_t)jj * SS] != 0 ? 1u : 0u) << jj;
        maskbits[((size_t)b * SS + sk) * 64 + w] = bits;
    }
}

// ---------------------------------------------------------------------------
// Shared gemm_bt mainloop: C[128x128] += A[128xK] * B^T, A/B row-major [*][1024] bf16
// ---------------------------------------------------------------------------
__device__ __forceinline__ void gemm_mainloop(
    const ushort_t* __restrict__ A, const ushort_t* __restrict__ Bm,
    int m0, int n0, f32x4 acc[4][4], ushort_t* As, ushort_t* Bs)
{
    const int tid  = threadIdx.x;
    const int wave = tid >> 6, lane = tid & 63;
    const int r16  = lane >> 2;          // row within 16-row chunk
    const int c8   = (lane & 3) * 8;     // ushort col within 32-wide row
    const int lane15 = lane & 15, quad = lane >> 4;
    const int wm = wave >> 1, wn = wave & 1;

    #pragma unroll 1
    for (int kt = 0; kt < 32; ++kt) {
        const int k0 = kt * 32;
        __syncthreads();
        const ushort_t* ga = A  + (size_t)(m0 + wave * 32 + r16) * 1024 + k0 + c8;
        load_lds16(ga,             As + wave * 1024);
        load_lds16(ga + 16 * 1024, As + wave * 1024 + 512);
        const ushort_t* gb = Bm + (size_t)(n0 + wave * 32 + r16) * 1024 + k0 + c8;
        load_lds16(gb,             Bs + wave * 1024);
        load_lds16(gb + 16 * 1024, Bs + wave * 1024 + 512);
        __syncthreads();

        short8 a[4], bf[4];
        #pragma unroll
        for (int i = 0; i < 4; ++i)
            a[i] = *(const short8*)&As[(wm * 64 + i * 16 + lane15) * 32 + quad * 8];
        #pragma unroll
        for (int j = 0; j < 4; ++j)
            bf[j] = *(const short8*)&Bs[(wn * 64 + j * 16 + lane15) * 32 + quad * 8];
        #pragma unroll
        for (int i = 0; i < 4; ++i)
            #pragma unroll
            for (int j = 0; j < 4; ++j)
                acc[i][j] = __builtin_amdgcn_mfma_f32_16x16x32_bf16(a[i], bf[j], acc[i][j], 0, 0, 0);
    }
}

// ---------------------------------------------------------------------------
// Kernel 2: QKV projections. z=0: Q (scaled, ->[B,H,S,D]); z=1: K; z=2: V -> [B,H,D,S']
// ---------------------------------------------------------------------------
__global__ __launch_bounds__(256) void gemm_qkv(
    ushort_t* __restrict__ wsb,
    const float* __restrict__ bq, const float* __restrict__ bk, const float* __restrict__ bv)
{
    __shared__ ushort_t As[128 * 32], Bs[128 * 32];
    const int z = blockIdx.z;
    const ushort_t* A  = wsb + (z == 0 ? QB_OFF : z == 1 ? KB_OFF : VB_OFF);
    const ushort_t* Bm = wsb + (z == 0 ? WQ_OFF : z == 1 ? WK_OFF : WV_OFF);
    const float* bias  = (z == 0) ? bq : (z == 1) ? bk : bv;
    ushort_t* dst      = wsb + (z == 0 ? QH_OFF : z == 1 ? KH_OFF : VT_OFF);
    const int m0 = blockIdx.y * 128, n0 = blockIdx.x * 128;

    f32x4 acc[4][4];
    #pragma unroll
    for (int i = 0; i < 4; ++i)
        #pragma unroll
        for (int j = 0; j < 4; ++j) acc[i][j] = (f32x4){0.f, 0.f, 0.f, 0.f};

    gemm_mainloop(A, Bm, m0, n0, acc, As, Bs);

    const int tid = threadIdx.x, wave = tid >> 6, lane = tid & 63;
    const int lane15 = lane & 15, quad = lane >> 4;
    const int wm = wave >> 1, wn = wave & 1;
    const float scale = (z == 0) ? 0.180336880111f : 1.0f;  // 1/sqrt(64) * log2(e)

    #pragma unroll
    for (int i = 0; i < 4; ++i) {
        #pragma unroll
        for (int j = 0; j < 4; ++j) {
            int col = n0 + wn * 64 + j * 16 + lane15;
            float bv_ = bias[col];
            int hh = col >> 6, d = col & 63;
            #pragma unroll
            for (int r = 0; r < 4; ++r) {
                int row = m0 + wm * 64 + i * 16 + quad * 4 + r;
                int bb = row >> 11, s = row & 2047;
                float val = (acc[i][j][r] + bv_) * scale;
                size_t off;
                if (z < 2) {
                    off = (((size_t)bb * HH + hh) * SS + s) * DD + d;
                } else {
                    // k'-permutation within each 128-token block: k' = (k&15)*8 + (k>>4)
                    int kk = s & 127;
                    int sp = (s & ~127) + ((kk & 15) << 3) + (kk >> 4);
                    off = (((size_t)bb * HH + hh) * DD + d) * SS + sp;
                }
                dst[off] = f2bf(val);
            }
        }
    }
}

// ---------------------------------------------------------------------------
// Kernel 3: flash attention. Block = (128 q-rows) x (b,h). 16 k-tiles of 128.
// Each wave owns 32 complete q-rows. Q fragments live in registers.
// LDS layouts are XOR-chunk-swizzled (chunk ^= row&7) so all MFMA fragment
// reads are ~2-way (free); swizzle applied on the per-lane GLOBAL address at
// staging time (LDS image stays contiguous for global_load_lds).
// P uses k'-permuted columns (k' = (k&15)*8 + k>>4) so each lane's 8 softmax
// values are LDS-contiguous -> single ds_write_b128. V global layout is
// identically k'-permuted (see gemm_qkv z==2 epilogue).
// ---------------------------------------------------------------------------
__global__ __launch_bounds__(256, 3) void attn_kernel(
    const ushort_t* __restrict__ wsb, const unsigned* __restrict__ maskbits,
    ushort_t* __restrict__ ctx)
{
    __shared__ ushort_t Ps[128 * 128];    // 32 KB; first 16 KB aliased as Ks[128][64]
    __shared__ ushort_t Vts[64 * 128];    // 16 KB
    ushort_t* Ks = Ps;

    const int tid  = threadIdx.x;
    const int wave = tid >> 6, lane = tid & 63;
    const int lane15 = lane & 15, quad = lane >> 4;
    const int sw7 = lane15 & 7;           // swizzle key for fragment reads
    const int bh = blockIdx.y;            // b*16 + h
    const int b  = bh >> 4, h = bh & 15;
    const int q0 = blockIdx.x * 128;

    const ushort_t* Qh  = wsb + QH_OFF;
    const ushort_t* Kh  = wsb + KH_OFF;
    const ushort_t* VhT = wsb + VT_OFF;

    // Q fragments (loop-invariant) straight to registers
    short8 qfrag[2][2];
    #pragma unroll
    for (int i = 0; i < 2; ++i)
        #pragma unroll
        for (int ks = 0; ks < 2; ++ks)
            qfrag[i][ks] = *(const short8*)(Qh +
                ((size_t)bh * SS + q0 + wave * 32 + i * 16 + lane15) * DD + ks * 32 + quad * 8);

    f32x4 s_acc[2][8];
    f32x4 o_acc[2][4];
    float m_st[2][4], l_st[2][4];
    #pragma unroll
    for (int i = 0; i < 2; ++i) {
        #pragma unroll
        for (int jd = 0; jd < 4; ++jd) o_acc[i][jd] = (f32x4){0.f, 0.f, 0.f, 0.f};
        #pragma unroll
        for (int r = 0; r < 4; ++r) { m_st[i][r] = -1e30f; l_st[i][r] = 0.f; }
    }

    #pragma unroll 1
    for (int kt = 0; kt < 16; ++kt) {
        const int k0 = kt * 128;
        __syncthreads();  // prev PV done reading Ps/Vts

        // stage K tile [128 sk][8 chunks] with swizzled global gather
        const ushort_t* Kbase = Kh + ((size_t)bh * SS + k0) * DD;
        #pragma unroll
        for (int cc = 0; cc < 4; ++cc) {
            int n = (wave * 4 + cc) * 64 + lane;       // LDS chunk id
            int row = n >> 3;
            int c = (n & 7) ^ (row & 7);               // logical chunk
            load_lds16(Kbase + row * 64 + c * 8, Ks + (wave * 4 + cc) * 512);
        }
        // stage Vt tile [64 d][16 chunks] (global is k'-permuted already)
        const ushort_t* Vbase = VhT + ((size_t)bh * DD) * SS + k0;
        #pragma unroll
        for (int cc = 0; cc < 4; ++cc) {
            int n = (wave * 4 + cc) * 64 + lane;
            int d = n >> 4;
            int c = (n & 15) ^ (d & 7);
            load_lds16(Vbase + (size_t)d * SS + c * 8, Vts + (wave * 4 + cc) * 512);
        }
        __syncthreads();  // staging visible

        // mask word per j-block: word qw covers q rows [q0+wave*32, +32)
        unsigned mw[8];
        {
            const int qw = (q0 >> 5) + wave;
            #pragma unroll
            for (int j = 0; j < 8; ++j) {
                int sk = k0 + j * 16 + lane15;
                mw[j] = maskbits[((size_t)b * SS + sk) * 64 + qw];
            }
        }

        // S = Q K^T (scale+log2e folded into Q); wave covers rows wave*32..+32
        #pragma unroll
        for (int i = 0; i < 2; ++i)
            #pragma unroll
            for (int j = 0; j < 8; ++j) s_acc[i][j] = (f32x4){0.f, 0.f, 0.f, 0.f};
        #pragma unroll
        for (int ks = 0; ks < 2; ++ks) {
            #pragma unroll
            for (int j = 0; j < 8; ++j) {
                short8 bf = *(const short8*)&Ks[(j * 16 + lane15) * 64 +
                                                (((ks * 4 + quad) ^ sw7) << 3)];
                s_acc[0][j] = __builtin_amdgcn_mfma_f32_16x16x32_bf16(qfrag[0][ks], bf, s_acc[0][j], 0, 0, 0);
                s_acc[1][j] = __builtin_amdgcn_mfma_f32_16x16x32_bf16(qfrag[1][ks], bf, s_acc[1][j], 0, 0, 0);
            }
        }

        __syncthreads();  // all waves done reading Ks before Ps overwrites it

        // online softmax (base-2): P = bit * 2^(s - m_new). Row = wave*32+i*16+quad*4+r.
        #pragma unroll
        for (int i = 0; i < 2; ++i) {
            #pragma unroll
            for (int r = 0; r < 4; ++r) {
                const int bit = i * 16 + quad * 4 + r;   // row % 32
                float mx = -1e30f;
                #pragma unroll
                for (int j = 0; j < 8; ++j) mx = fmaxf(mx, s_acc[i][j][r]);
                mx = fmaxf(mx, __shfl_xor(mx, 1));
                mx = fmaxf(mx, __shfl_xor(mx, 2));
                mx = fmaxf(mx, __shfl_xor(mx, 4));
                mx = fmaxf(mx, __shfl_xor(mx, 8));
                float mold = m_st[i][r];
                float mnew = fmaxf(mold, mx);
                float alpha = exp2f(mold - mnew);
                m_st[i][r] = mnew;
                float sum = 0.f;
                short8 pk;
                #pragma unroll
                for (int j = 0; j < 8; ++j) {
                    float p = exp2f(s_acc[i][j][r] - mnew);
                    p = ((mw[j] >> bit) & 1u) ? p : 0.f;
                    sum += p;
                    pk[j] = (short)f2bf(p);
                }
                const int row = wave * 32 + i * 16 + quad * 4 + r;
                // P[row][k'] : lane's 8 values are k' = lane15*8 + j (chunk = lane15)
                *(short8*)&Ps[row * 128 + ((lane15 ^ (row & 7)) << 3)] = pk;
                sum += __shfl_xor(sum, 1);
                sum += __shfl_xor(sum, 2);
                sum += __shfl_xor(sum, 4);
                sum += __shfl_xor(sum, 8);
                l_st[i][r] = l_st[i][r] * alpha + sum;
                #pragma unroll
                for (int jd = 0; jd < 4; ++jd) o_acc[i][jd][r] *= alpha;
            }
        }

        __syncthreads();  // Ps fully written

        // O += P V : wave's 32 q rows x all 64 d cols (k' space, both permuted)
        #pragma unroll
        for (int kb = 0; kb < 4; ++kb) {
            short8 ap[2], bv_[4];
            #pragma unroll
            for (int i = 0; i < 2; ++i)
                ap[i] = *(const short8*)&Ps[(wave * 32 + i * 16 + lane15) * 128 +
                                            (((kb * 4 + quad) ^ sw7) << 3)];
            #pragma unroll
            for (int jd = 0; jd < 4; ++jd)
                bv_[jd] = *(const short8*)&Vts[(jd * 16 + lane15) * 128 +
                                               (((kb * 4 + quad) ^ sw7) << 3)];
            #pragma unroll
            for (int i = 0; i < 2; ++i)
                #pragma unroll
                for (int jd = 0; jd < 4; ++jd)
                    o_acc[i][jd] = __builtin_amdgcn_mfma_f32_16x16x32_bf16(ap[i], bv_[jd], o_acc[i][jd], 0, 0, 0);
        }
    }

    // epilogue: ctx[b*S + q][h*64 + d] = O / l
    #pragma unroll
    for (int i = 0; i < 2; ++i) {
        #pragma unroll
        for (int r = 0; r < 4; ++r) {
            int row = q0 + wave * 32 + i * 16 + quad * 4 + r;
            float inv = 1.0f / l_st[i][r];
            #pragma unroll
            for (int jd = 0; jd < 4; ++jd) {
                int col = h * DD + jd * 16 + lane15;
                ctx[((size_t)b * SS + row) * EE + col] = f2bf(o_acc[i][jd][r] * inv);
            }
        }
    }
}

// ---------------------------------------------------------------------------
// Kernel 4: out = ctx @ Wo^T + bo  (fp32 output)
// ---------------------------------------------------------------------------
__global__ __launch_bounds__(256) void gemm_out(
    const ushort_t* __restrict__ wsb, const float* __restrict__ bo, float* __restrict__ out)
{
    __shared__ ushort_t As[128 * 32], Bs[128 * 32];
    const ushort_t* A  = wsb + CTX_OFF;
    const ushort_t* Bm = wsb + WO_OFF;
    const int m0 = blockIdx.y * 128, n0 = blockIdx.x * 128;

    f32x4 acc[4][4];
    #pragma unroll
    for (int i = 0; i < 4; ++i)
        #pragma unroll
        for (int j = 0; j < 4; ++j) acc[i][j] = (f32x4){0.f, 0.f, 0.f, 0.f};

    gemm_mainloop(A, Bm, m0, n0, acc, As, Bs);

    const int tid = threadIdx.x, wave = tid >> 6, lane = tid & 63;
    const int lane15 = lane & 15, quad = lane >> 4;
    const int wm = wave >> 1, wn = wave & 1;

    #pragma unroll
    for (int i = 0; i < 4; ++i) {
        #pragma unroll
        for (int j = 0; j < 4; ++j) {
            int col = n0 + wn * 64 + j * 16 + lane15;
            float bv_ = bo[col];
            #pragma unroll
            for (int r = 0; r < 4; ++r) {
                int row = m0 + wm * 64 + i * 16 + quad * 4 + r;
                out[(size_t)row * EE + col] = acc[i][j][r] + bv_;
            }
        }
    }
}

// ---------------------------------------------------------------------------
extern "C" void kernel_launch(void* const* d_in, const int* in_sizes, int n_in,
                              void* d_out, int out_size, void* d_ws, size_t ws_size,
                              hipStream_t stream) {
    const float* q    = (const float*)d_in[0];
    const float* k    = (const float*)d_in[1];
    const float* v    = (const float*)d_in[2];
    const int*   mask = (const int*)  d_in[3];
    const float* Wq   = (const float*)d_in[4];
    const float* bq   = (const float*)d_in[5];
    const float* Wk   = (const float*)d_in[6];
    const float* bk   = (const float*)d_in[7];
    const float* Wv   = (const float*)d_in[8];
    const float* bv   = (const float*)d_in[9];
    const float* Wo   = (const float*)d_in[10];
    const float* bo   = (const float*)d_in[11];

    ushort_t* wsb = (ushort_t*)d_ws;
    unsigned* maskbits = (unsigned*)(wsb + MB_OFF);

    prep_kernel<<<17408, 256, 0, stream>>>(q, k, v, mask, Wq, Wk, Wv, Wo, wsb, maskbits);
    gemm_qkv<<<dim3(8, 32, 3), 256, 0, stream>>>(wsb, bq, bk, bv);
    attn_kernel<<<dim3(16, 32), 256, 0, stream>>>(wsb, maskbits, wsb + CTX_OFF);
    gemm_out<<<dim3(8, 32), 256, 0, stream>>>(wsb, bo, (float*)d_out);
}

// Round 4
// 342.561 us; speedup vs baseline: 1.4593x; 1.4593x over previous
//
#include <hip/hip_runtime.h>

typedef unsigned short ushort_t;
typedef __attribute__((ext_vector_type(8))) short short8;
typedef __attribute__((ext_vector_type(4))) float f32x4;
typedef __attribute__((ext_vector_type(4))) unsigned short ushort4_t;

// Problem constants
#define BB 2
#define SS 2048
#define EE 1024
#define HH 16
#define DD 64
#define MM (BB*SS)   // 4096

// Workspace layout (ushort element offsets)
#define QB_OFF  0u          // q bf16 [M][E]; reused as ctx bf16 [M][E] after gemm_qkv
#define KB_OFF  4194304u
#define VB_OFF  8388608u
#define WQ_OFF  12582912u   // Wq bf16 [E][E]
#define WK_OFF  13631488u
#define WV_OFF  14680064u
#define WO_OFF  15728640u
#define QH_OFF  16777216u   // Qh bf16 [B][H][S][D] (pre-scaled by 0.125*log2e)
#define KH_OFF  20971520u   // Kh bf16 [B][H][S][D]
#define VT_OFF  25165824u   // VhT bf16 [B][H][D][S'] (S k'-permuted per 128-block)
#define CTX_OFF QB_OFF      // ctx aliases dead q-bf16 region
#define MB_OFF  29360128u   // maskbitsT u32 [B][S(sk)][S/32] (byte off = 2*MB_OFF)

__device__ __forceinline__ ushort_t f2bf(float x) {
    unsigned u = __builtin_bit_cast(unsigned, x);
    u += 0x7FFFu + ((u >> 16) & 1u);
    return (ushort_t)(u >> 16);
}

__device__ __forceinline__ void load_lds16(const void* g, void* l) {
    __builtin_amdgcn_global_load_lds((const __attribute__((address_space(1))) void*)g,
                                     (__attribute__((address_space(3))) void*)l, 16, 0, 0);
}

// ---------------------------------------------------------------------------
// Kernel 1: cast fp32->bf16 (q,k,v,Wq,Wk,Wv,Wo) + transposed mask bit-pack
// ---------------------------------------------------------------------------
__global__ __launch_bounds__(256) void prep_kernel(
    const float* __restrict__ q, const float* __restrict__ k, const float* __restrict__ v,
    const int* __restrict__ mask,
    const float* __restrict__ Wq, const float* __restrict__ Wk,
    const float* __restrict__ Wv, const float* __restrict__ Wo,
    ushort_t* __restrict__ wsb, unsigned* __restrict__ maskbits)
{
    int g = blockIdx.x;
    if (g < 16384) {
        int idx = g * 256 + threadIdx.x;  // float4 index
        const float* src; ushort_t* dst; int rel;
        if      (idx < 1048576) { src = q;  dst = wsb + QB_OFF; rel = idx; }
        else if (idx < 2097152) { src = k;  dst = wsb + KB_OFF; rel = idx - 1048576; }
        else if (idx < 3145728) { src = v;  dst = wsb + VB_OFF; rel = idx - 2097152; }
        else if (idx < 3407872) { src = Wq; dst = wsb + WQ_OFF; rel = idx - 3145728; }
        else if (idx < 3670016) { src = Wk; dst = wsb + WK_OFF; rel = idx - 3407872; }
        else if (idx < 3932160) { src = Wv; dst = wsb + WV_OFF; rel = idx - 3670016; }
        else                    { src = Wo; dst = wsb + WO_OFF; rel = idx - 3932160; }
        f32x4 val = ((const f32x4*)src)[rel];
        ushort4_t o;
        o.x = f2bf(val.x); o.y = f2bf(val.y); o.z = f2bf(val.z); o.w = f2bf(val.w);
        ((ushort4_t*)dst)[rel] = o;
    } else {
        // maskbitsT[b][sk][w] bit j = (mask[b][0][w*32+j][sk] != 0)
        int t = (g - 16384) * 256 + threadIdx.x;   // 0..262143
        int b   = t >> 17;
        int rem = t & 131071;
        int w   = rem >> 11;        // 0..63
        int sk  = rem & 2047;       // consecutive lanes -> consecutive sk (coalesced loads)
        unsigned bits = 0;
        const int* mp = mask + ((size_t)b * SS + (size_t)w * 32) * SS + sk;
        #pragma unroll
        for (int jj = 0; jj < 32; ++jj)
            bits |= (mp[(size_t)jj * SS] != 0 ? 1u : 0u) << jj;
        maskbits[((size_t)b * SS + sk) * 64 + w] = bits;
    }
}

// ---------------------------------------------------------------------------
// Shared gemm_bt mainloop: C[128x128] += A[128xK] * B^T, A/B row-major [*][1024] bf16
// ---------------------------------------------------------------------------
__device__ __forceinline__ void gemm_mainloop(
    const ushort_t* __restrict__ A, const ushort_t* __restrict__ Bm,
    int m0, int n0, f32x4 acc[4][4], ushort_t* As, ushort_t* Bs)
{
    const int tid  = threadIdx.x;
    const int wave = tid >> 6, lane = tid & 63;
    const int r16  = lane >> 2;          // row within 16-row chunk
    const int c8   = (lane & 3) * 8;     // ushort col within 32-wide row
    const int lane15 = lane & 15, quad = lane >> 4;
    const int wm = wave >> 1, wn = wave & 1;

    #pragma unroll 1
    for (int kt = 0; kt < 32; ++kt) {
        const int k0 = kt * 32;
        __syncthreads();
        const ushort_t* ga = A  + (size_t)(m0 + wave * 32 + r16) * 1024 + k0 + c8;
        load_lds16(ga,             As + wave * 1024);
        load_lds16(ga + 16 * 1024, As + wave * 1024 + 512);
        const ushort_t* gb = Bm + (size_t)(n0 + wave * 32 + r16) * 1024 + k0 + c8;
        load_lds16(gb,             Bs + wave * 1024);
        load_lds16(gb + 16 * 1024, Bs + wave * 1024 + 512);
        __syncthreads();

        short8 a[4], bf[4];
        #pragma unroll
        for (int i = 0; i < 4; ++i)
            a[i] = *(const short8*)&As[(wm * 64 + i * 16 + lane15) * 32 + quad * 8];
        #pragma unroll
        for (int j = 0; j < 4; ++j)
            bf[j] = *(const short8*)&Bs[(wn * 64 + j * 16 + lane15) * 32 + quad * 8];
        #pragma unroll
        for (int i = 0; i < 4; ++i)
            #pragma unroll
            for (int j = 0; j < 4; ++j)
                acc[i][j] = __builtin_amdgcn_mfma_f32_16x16x32_bf16(a[i], bf[j], acc[i][j], 0, 0, 0);
    }
}

// ---------------------------------------------------------------------------
// Kernel 2: QKV projections. z=0: Q (scaled, ->[B,H,S,D]); z=1: K; z=2: V -> [B,H,D,S']
// ---------------------------------------------------------------------------
__global__ __launch_bounds__(256) void gemm_qkv(
    ushort_t* __restrict__ wsb,
    const float* __restrict__ bq, const float* __restrict__ bk, const float* __restrict__ bv)
{
    __shared__ ushort_t As[128 * 32], Bs[128 * 32];
    const int z = blockIdx.z;
    const ushort_t* A  = wsb + (z == 0 ? QB_OFF : z == 1 ? KB_OFF : VB_OFF);
    const ushort_t* Bm = wsb + (z == 0 ? WQ_OFF : z == 1 ? WK_OFF : WV_OFF);
    const float* bias  = (z == 0) ? bq : (z == 1) ? bk : bv;
    ushort_t* dst      = wsb + (z == 0 ? QH_OFF : z == 1 ? KH_OFF : VT_OFF);
    const int m0 = blockIdx.y * 128, n0 = blockIdx.x * 128;

    f32x4 acc[4][4];
    #pragma unroll
    for (int i = 0; i < 4; ++i)
        #pragma unroll
        for (int j = 0; j < 4; ++j) acc[i][j] = (f32x4){0.f, 0.f, 0.f, 0.f};

    gemm_mainloop(A, Bm, m0, n0, acc, As, Bs);

    const int tid = threadIdx.x, wave = tid >> 6, lane = tid & 63;
    const int lane15 = lane & 15, quad = lane >> 4;
    const int wm = wave >> 1, wn = wave & 1;
    const float scale = (z == 0) ? 0.180336880111f : 1.0f;  // 1/sqrt(64) * log2(e)

    #pragma unroll
    for (int i = 0; i < 4; ++i) {
        #pragma unroll
        for (int j = 0; j < 4; ++j) {
            int col = n0 + wn * 64 + j * 16 + lane15;
            float bv_ = bias[col];
            int hh = col >> 6, d = col & 63;
            #pragma unroll
            for (int r = 0; r < 4; ++r) {
                int row = m0 + wm * 64 + i * 16 + quad * 4 + r;
                int bb = row >> 11, s = row & 2047;
                float val = (acc[i][j][r] + bv_) * scale;
                size_t off;
                if (z < 2) {
                    off = (((size_t)bb * HH + hh) * SS + s) * DD + d;
                } else {
                    // k'-permutation within each 128-token block: k' = (k&15)*8 + (k>>4)
                    int kk = s & 127;
                    int sp = (s & ~127) + ((kk & 15) << 3) + (kk >> 4);
                    off = (((size_t)bb * HH + hh) * DD + d) * SS + sp;
                }
                dst[off] = f2bf(val);
            }
        }
    }
}

// ---------------------------------------------------------------------------
// Kernel 3: flash attention. Block = (128 q-rows) x (b,h). 16 k-tiles of 128.
// Each wave owns 32 complete q-rows. Q fragments live in registers.
// LDS layouts are XOR-chunk-swizzled (chunk ^= row&7) so all MFMA fragment
// reads are ~2-way (free). P uses k'-permuted columns so each lane's 8
// softmax values are one ds_write_b128; V global layout matches.
// __launch_bounds__(256,2): R3's (256,3) forced VGPR=84 -> massive scratch
// spills (FETCH 397 MB, WRITE 143 MB). 2 leaves the allocator room (~130-160).
// ---------------------------------------------------------------------------
__global__ __launch_bounds__(256, 2) void attn_kernel(
    const ushort_t* __restrict__ wsb, const unsigned* __restrict__ maskbits,
    ushort_t* __restrict__ ctx)
{
    __shared__ ushort_t Ps[128 * 128];    // 32 KB; first 16 KB aliased as Ks[128][64]
    __shared__ ushort_t Vts[64 * 128];    // 16 KB
    ushort_t* Ks = Ps;

    const int tid  = threadIdx.x;
    const int wave = tid >> 6, lane = tid & 63;
    const int lane15 = lane & 15, quad = lane >> 4;
    const int sw7 = lane15 & 7;           // swizzle key for fragment reads
    const int bh = blockIdx.y;            // b*16 + h
    const int b  = bh >> 4, h = bh & 15;
    const int q0 = blockIdx.x * 128;

    const ushort_t* Qh  = wsb + QH_OFF;
    const ushort_t* Kh  = wsb + KH_OFF;
    const ushort_t* VhT = wsb + VT_OFF;

    // Q fragments (loop-invariant) straight to registers
    short8 qfrag[2][2];
    #pragma unroll
    for (int i = 0; i < 2; ++i)
        #pragma unroll
        for (int ks = 0; ks < 2; ++ks)
            qfrag[i][ks] = *(const short8*)(Qh +
                ((size_t)bh * SS + q0 + wave * 32 + i * 16 + lane15) * DD + ks * 32 + quad * 8);

    f32x4 s_acc[2][8];
    f32x4 o_acc[2][4];
    float m_st[2][4], l_st[2][4];
    #pragma unroll
    for (int i = 0; i < 2; ++i) {
        #pragma unroll
        for (int jd = 0; jd < 4; ++jd) o_acc[i][jd] = (f32x4){0.f, 0.f, 0.f, 0.f};
        #pragma unroll
        for (int r = 0; r < 4; ++r) { m_st[i][r] = -1e30f; l_st[i][r] = 0.f; }
    }

    #pragma unroll 1
    for (int kt = 0; kt < 16; ++kt) {
        const int k0 = kt * 128;
        __syncthreads();  // prev PV done reading Ps/Vts

        // stage K tile [128 sk][8 chunks] with swizzled global gather
        const ushort_t* Kbase = Kh + ((size_t)bh * SS + k0) * DD;
        #pragma unroll
        for (int cc = 0; cc < 4; ++cc) {
            int n = (wave * 4 + cc) * 64 + lane;       // LDS chunk id
            int row = n >> 3;
            int c = (n & 7) ^ (row & 7);               // logical chunk
            load_lds16(Kbase + row * 64 + c * 8, Ks + (wave * 4 + cc) * 512);
        }
        // stage Vt tile [64 d][16 chunks] (global is k'-permuted already)
        const ushort_t* Vbase = VhT + ((size_t)bh * DD) * SS + k0;
        #pragma unroll
        for (int cc = 0; cc < 4; ++cc) {
            int n = (wave * 4 + cc) * 64 + lane;
            int d = n >> 4;
            int c = (n & 15) ^ (d & 7);
            load_lds16(Vbase + (size_t)d * SS + c * 8, Vts + (wave * 4 + cc) * 512);
        }
        __syncthreads();  // staging visible

        // mask word per j-block: word qw covers q rows [q0+wave*32, +32)
        unsigned mw[8];
        {
            const int qw = (q0 >> 5) + wave;
            #pragma unroll
            for (int j = 0; j < 8; ++j) {
                int sk = k0 + j * 16 + lane15;
                mw[j] = maskbits[((size_t)b * SS + sk) * 64 + qw];
            }
        }

        // S = Q K^T (scale+log2e folded into Q); wave covers rows wave*32..+32
        #pragma unroll
        for (int i = 0; i < 2; ++i)
            #pragma unroll
            for (int j = 0; j < 8; ++j) s_acc[i][j] = (f32x4){0.f, 0.f, 0.f, 0.f};
        #pragma unroll
        for (int ks = 0; ks < 2; ++ks) {
            #pragma unroll
            for (int j = 0; j < 8; ++j) {
                short8 bf = *(const short8*)&Ks[(j * 16 + lane15) * 64 +
                                                (((ks * 4 + quad) ^ sw7) << 3)];
                s_acc[0][j] = __builtin_amdgcn_mfma_f32_16x16x32_bf16(qfrag[0][ks], bf, s_acc[0][j], 0, 0, 0);
                s_acc[1][j] = __builtin_amdgcn_mfma_f32_16x16x32_bf16(qfrag[1][ks], bf, s_acc[1][j], 0, 0, 0);
            }
        }

        __syncthreads();  // all waves done reading Ks before Ps overwrites it

        // online softmax (base-2): P = bit * 2^(s - m_new). Row = wave*32+i*16+quad*4+r.
        #pragma unroll
        for (int i = 0; i < 2; ++i) {
            #pragma unroll
            for (int r = 0; r < 4; ++r) {
                const int bit = i * 16 + quad * 4 + r;   // row % 32
                float mx = -1e30f;
                #pragma unroll
                for (int j = 0; j < 8; ++j) mx = fmaxf(mx, s_acc[i][j][r]);
                mx = fmaxf(mx, __shfl_xor(mx, 1));
                mx = fmaxf(mx, __shfl_xor(mx, 2));
                mx = fmaxf(mx, __shfl_xor(mx, 4));
                mx = fmaxf(mx, __shfl_xor(mx, 8));
                float mold = m_st[i][r];
                float mnew = fmaxf(mold, mx);
                float alpha = exp2f(mold - mnew);
                m_st[i][r] = mnew;
                float sum = 0.f;
                short8 pk;
                #pragma unroll
                for (int j = 0; j < 8; ++j) {
                    float p = exp2f(s_acc[i][j][r] - mnew);
                    p = ((mw[j] >> bit) & 1u) ? p : 0.f;
                    sum += p;
                    pk[j] = (short)f2bf(p);
                }
                const int row = wave * 32 + i * 16 + quad * 4 + r;
                // P[row][k'] : lane's 8 values are k' = lane15*8 + j (chunk = lane15)
                *(short8*)&Ps[row * 128 + ((lane15 ^ (row & 7)) << 3)] = pk;
                sum += __shfl_xor(sum, 1);
                sum += __shfl_xor(sum, 2);
                sum += __shfl_xor(sum, 4);
                sum += __shfl_xor(sum, 8);
                l_st[i][r] = l_st[i][r] * alpha + sum;
                #pragma unroll
                for (int jd = 0; jd < 4; ++jd) o_acc[i][jd][r] *= alpha;
            }
        }

        __syncthreads();  // Ps fully written

        // O += P V : wave's 32 q rows x all 64 d cols (k' space, both permuted)
        #pragma unroll
        for (int kb = 0; kb < 4; ++kb) {
            short8 ap[2], bv_[4];
            #pragma unroll
            for (int i = 0; i < 2; ++i)
                ap[i] = *(const short8*)&Ps[(wave * 32 + i * 16 + lane15) * 128 +
                                            (((kb * 4 + quad) ^ sw7) << 3)];
            #pragma unroll
            for (int jd = 0; jd < 4; ++jd)
                bv_[jd] = *(const short8*)&Vts[(jd * 16 + lane15) * 128 +
                                               (((kb * 4 + quad) ^ sw7) << 3)];
            #pragma unroll
            for (int i = 0; i < 2; ++i)
                #pragma unroll
                for (int jd = 0; jd < 4; ++jd)
                    o_acc[i][jd] = __builtin_amdgcn_mfma_f32_16x16x32_bf16(ap[i], bv_[jd], o_acc[i][jd], 0, 0, 0);
        }
    }

    // epilogue: ctx[b*S + q][h*64 + d] = O / l
    #pragma unroll
    for (int i = 0; i < 2; ++i) {
        #pragma unroll
        for (int r = 0; r < 4; ++r) {
            int row = q0 + wave * 32 + i * 16 + quad * 4 + r;
            float inv = 1.0f / l_st[i][r];
            #pragma unroll
            for (int jd = 0; jd < 4; ++jd) {
                int col = h * DD + jd * 16 + lane15;
                ctx[((size_t)b * SS + row) * EE + col] = f2bf(o_acc[i][jd][r] * inv);
            }
        }
    }
}

// ---------------------------------------------------------------------------
// Kernel 4: out = ctx @ Wo^T + bo  (fp32 output)
// ---------------------------------------------------------------------------
__global__ __launch_bounds__(256) void gemm_out(
    const ushort_t* __restrict__ wsb, const float* __restrict__ bo, float* __restrict__ out)
{
    __shared__ ushort_t As[128 * 32], Bs[128 * 32];
    const ushort_t* A  = wsb + CTX_OFF;
    const ushort_t* Bm = wsb + WO_OFF;
    const int m0 = blockIdx.y * 128, n0 = blockIdx.x * 128;

    f32x4 acc[4][4];
    #pragma unroll
    for (int i = 0; i < 4; ++i)
        #pragma unroll
        for (int j = 0; j < 4; ++j) acc[i][j] = (f32x4){0.f, 0.f, 0.f, 0.f};

    gemm_mainloop(A, Bm, m0, n0, acc, As, Bs);

    const int tid = threadIdx.x, wave = tid >> 6, lane = tid & 63;
    const int lane15 = lane & 15, quad = lane >> 4;
    const int wm = wave >> 1, wn = wave & 1;

    #pragma unroll
    for (int i = 0; i < 4; ++i) {
        #pragma unroll
        for (int j = 0; j < 4; ++j) {
            int col = n0 + wn * 64 + j * 16 + lane15;
            float bv_ = bo[col];
            #pragma unroll
            for (int r = 0; r < 4; ++r) {
                int row = m0 + wm * 64 + i * 16 + quad * 4 + r;
                out[(size_t)row * EE + col] = acc[i][j][r] + bv_;
            }
        }
    }
}

// ---------------------------------------------------------------------------
extern "C" void kernel_launch(void* const* d_in, const int* in_sizes, int n_in,
                              void* d_out, int out_size, void* d_ws, size_t ws_size,
                              hipStream_t stream) {
    const float* q    = (const float*)d_in[0];
    const float* k    = (const float*)d_in[1];
    const float* v    = (const float*)d_in[2];
    const int*   mask = (const int*)  d_in[3];
    const float* Wq   = (const float*)d_in[4];
    const float* bq   = (const float*)d_in[5];
    const float* Wk   = (const float*)d_in[6];
    const float* bk   = (const float*)d_in[7];
    const float* Wv   = (const float*)d_in[8];
    const float* bv   = (const float*)d_in[9];
    const float* Wo   = (const float*)d_in[10];
    const float* bo   = (const float*)d_in[11];

    ushort_t* wsb = (ushort_t*)d_ws;
    unsigned* maskbits = (unsigned*)(wsb + MB_OFF);

    prep_kernel<<<17408, 256, 0, stream>>>(q, k, v, mask, Wq, Wk, Wv, Wo, wsb, maskbits);
    gemm_qkv<<<dim3(8, 32, 3), 256, 0, stream>>>(wsb, bq, bk, bv);
    attn_kernel<<<dim3(16, 32), 256, 0, stream>>>(wsb, maskbits, wsb + CTX_OFF);
    gemm_out<<<dim3(8, 32), 256, 0, stream>>>(wsb, bo, (float*)d_out);
}